// Round 2
// baseline (679.417 us; speedup 1.0000x reference)
//
#include <hip/hip_runtime.h>
#include <cstdint>
#include <cstddef>

typedef _Float16 f16;
typedef _Float16 f16x8 __attribute__((ext_vector_type(8)));
typedef _Float16 f16x4 __attribute__((ext_vector_type(4)));
typedef float    f32x4 __attribute__((ext_vector_type(4)));

#define AS1 __attribute__((address_space(1)))
#define AS3 __attribute__((address_space(3)))

static constexpr int BB = 8;      // batch
static constexpr int SS = 2048;   // sequence
static constexpr int DD = 1024;   // model dim
static constexpr int MTOT = BB * SS; // 16384

// ---------------------------------------------------------------------------
// elementwise cast f32 -> f16 (vectorized float4 -> f16x4)
// ---------------------------------------------------------------------------
__global__ __launch_bounds__(256) void cast_f32_f16(const float* __restrict__ src,
                                                    f16* __restrict__ dst, int n4) {
  int i = blockIdx.x * 256 + threadIdx.x;
  if (i < n4) {
    const float4 f = reinterpret_cast<const float4*>(src)[i];
    f16x4 o = { (f16)f.x, (f16)f.y, (f16)f.z, (f16)f.w };
    reinterpret_cast<f16x4*>(dst)[i] = o;
  }
}

// ---------------------------------------------------------------------------
// weight transpose + cast: WT[n][k] = (f16)W[k][n], D x D
// ---------------------------------------------------------------------------
__global__ __launch_bounds__(256) void transpose_cast_wt(const float* __restrict__ W,
                                                         f16* __restrict__ WT, int D) {
  __shared__ float tile[32][33];
  const int bx = blockIdx.x * 32;  // col base (n)
  const int by = blockIdx.y * 32;  // row base (k)
  const int tx = threadIdx.x & 31;
  const int ty = threadIdx.x >> 5; // 0..7
  for (int i = ty; i < 32; i += 8) tile[i][tx] = W[(size_t)(by + i) * D + bx + tx];
  __syncthreads();
  for (int i = ty; i < 32; i += 8)
    WT[(size_t)(bx + i) * D + by + tx] = (f16)tile[tx][i];
}

// ---------------------------------------------------------------------------
// batched f16 transpose: dst[b][c][r] = src[b][r][c]
// ---------------------------------------------------------------------------
__global__ __launch_bounds__(256) void transpose_f16_batch(const f16* __restrict__ src,
                                                           f16* __restrict__ dst,
                                                           int R, int C) {
  __shared__ f16 tile[32][33];
  src += (size_t)blockIdx.z * R * C;
  dst += (size_t)blockIdx.z * R * C;
  const int bx = blockIdx.x * 32;  // c base
  const int by = blockIdx.y * 32;  // r base
  const int tx = threadIdx.x & 31;
  const int ty = threadIdx.x >> 5;
  for (int i = ty; i < 32; i += 8) tile[i][tx] = src[(size_t)(by + i) * C + bx + tx];
  __syncthreads();
  for (int i = ty; i < 32; i += 8) dst[(size_t)(bx + i) * R + by + tx] = tile[tx][i];
}

// ---------------------------------------------------------------------------
// GEMM: C[M,N] = A[M,K] * BT[N,K]^T  (+ epilogue), fp16 in, fp32 accumulate
// EPI: 0 = +bias -> f16
//      1 = plain -> f32 (scores)
//      2 = plain -> f16 (PV)
//      3 = +bias +resid(f32) -> f16 (Wo + residual)
//      4 = +bias, relu -> f16 (W1)
// m97 structure: 128x128 tile, BK=32, 4 waves (2x2), 4x4 16x16x32 frags/wave,
// global_load_lds(16B) staging, XOR chunk swizzle folded into global src addr.
// ---------------------------------------------------------------------------
template <int EPI>
__global__ __launch_bounds__(256) void gemm_f16(const f16* __restrict__ A,
                                                const f16* __restrict__ BT,
                                                void* __restrict__ Cout,
                                                const float* __restrict__ bias,
                                                const float* __restrict__ resid,
                                                int N, int K,
                                                size_t Abat, size_t Bbat, size_t Cbat) {
  __shared__ f16 Asm[128 * 32];
  __shared__ f16 Bsm[128 * 32];

  const int bz = blockIdx.z;
  A += (size_t)bz * Abat;
  BT += (size_t)bz * Bbat;
  const int m0 = blockIdx.y * 128;
  const int n0 = blockIdx.x * 128;
  const int tid = threadIdx.x;
  const int wid = tid >> 6;
  const int lane = tid & 63;
  const int wr = wid >> 1, wc = wid & 1;
  const int lg = lane >> 4, lr = lane & 15;

  f32x4 acc[4][4] = {};

  for (int k0 = 0; k0 < K; k0 += 32) {
    // ---- stage A (128x32) and B (128x32) tiles: 512 16B-chunks each ----
    // LDS chunk c holds row m=c>>2, slot s=c&3; slot s stores global k-chunk
    // kg = s ^ ((m>>1)&3)  (XOR swizzle; involution; applied on src addr).
#pragma unroll
    for (int it = 0; it < 2; ++it) {
      const int cbase = (it * 4 + wid) * 64;   // wave-uniform chunk base
      const int c = cbase + lane;
      const int m = c >> 2;
      const int kg = (c & 3) ^ ((m >> 1) & 3);
      const f16* srcA = A + (size_t)(m0 + m) * K + k0 + kg * 8;
      __builtin_amdgcn_global_load_lds((const AS1 void*)srcA,
                                       (AS3 void*)(Asm + cbase * 8), 16, 0, 0);
      const f16* srcB = BT + (size_t)(n0 + m) * K + k0 + kg * 8;
      __builtin_amdgcn_global_load_lds((const AS1 void*)srcB,
                                       (AS3 void*)(Bsm + cbase * 8), 16, 0, 0);
    }
    __syncthreads();

    // ---- fragments: a[i] = A[m][ (lg*8..+8) ], b[j] = BT[n][ (lg*8..+8) ] ----
    f16x8 a[4], b[4];
#pragma unroll
    for (int i = 0; i < 4; ++i) {
      const int m = wr * 64 + i * 16 + lr;
      const int sa = lg ^ ((m >> 1) & 3);
      a[i] = *(const f16x8*)(Asm + (m * 4 + sa) * 8);
      const int n = wc * 64 + i * 16 + lr;
      const int sb = lg ^ ((n >> 1) & 3);
      b[i] = *(const f16x8*)(Bsm + (n * 4 + sb) * 8);
    }
#pragma unroll
    for (int i = 0; i < 4; ++i)
#pragma unroll
      for (int j = 0; j < 4; ++j)
        acc[i][j] = __builtin_amdgcn_mfma_f32_16x16x32_f16(a[i], b[j], acc[i][j], 0, 0, 0);
    __syncthreads();
  }

  // ---- epilogue: D lane mapping col=lane&15, row=(lane>>4)*4+r ----
#pragma unroll
  for (int i = 0; i < 4; ++i) {
    const int row = m0 + wr * 64 + i * 16 + lg * 4;
#pragma unroll
    for (int j = 0; j < 4; ++j) {
      const int col = n0 + wc * 64 + j * 16 + lr;
      float bval = 0.f;
      if (EPI == 0 || EPI == 3 || EPI == 4) bval = bias[col];
#pragma unroll
      for (int r = 0; r < 4; ++r) {
        float v = acc[i][j][r] + bval;
        const size_t idx = (size_t)(row + r) * N + col;
        if (EPI == 3) v += resid[idx];            // residual only used with grid.z==1
        if (EPI == 4) v = fmaxf(v, 0.f);
        if (EPI == 1)
          ((float*)Cout)[(size_t)bz * Cbat + idx] = v;
        else
          ((f16*)Cout)[(size_t)bz * Cbat + idx] = (f16)v;
      }
    }
  }
}

// ---------------------------------------------------------------------------
// row softmax: one block per row of 2048 fp32 scores -> f16 probabilities
// ---------------------------------------------------------------------------
__global__ __launch_bounds__(256) void softmax_rows(const float* __restrict__ Sc,
                                                    f16* __restrict__ P) {
  const size_t row = blockIdx.x;
  const float* x = Sc + row * SS;
  f16* p = P + row * SS;
  const int t = threadIdx.x;
  const int wid = t >> 6, lane = t & 63;
  __shared__ float red[8];

  float v[8];
  float mx = -3.4e38f;
#pragma unroll
  for (int i = 0; i < 8; ++i) {
    v[i] = x[t + i * 256];
    mx = fmaxf(mx, v[i]);
  }
#pragma unroll
  for (int o = 32; o >= 1; o >>= 1) mx = fmaxf(mx, __shfl_xor(mx, o));
  if (lane == 0) red[wid] = mx;
  __syncthreads();
  mx = fmaxf(fmaxf(red[0], red[1]), fmaxf(red[2], red[3]));

  float sum = 0.f;
#pragma unroll
  for (int i = 0; i < 8; ++i) {
    v[i] = __expf(v[i] - mx);
    sum += v[i];
  }
#pragma unroll
  for (int o = 32; o >= 1; o >>= 1) sum += __shfl_xor(sum, o);
  if (lane == 0) red[4 + wid] = sum;
  __syncthreads();
  sum = red[4] + red[5] + red[6] + red[7];
  const float inv = 1.0f / sum;
#pragma unroll
  for (int i = 0; i < 8; ++i) p[t + i * 256] = (f16)(v[i] * inv);
}

// ---------------------------------------------------------------------------
// final head: out[m] = sum_k X[m][k]*W2[k] + b2 ; one wave per row
// ---------------------------------------------------------------------------
__global__ __launch_bounds__(256) void matvec_out(const f16* __restrict__ X,
                                                  const float* __restrict__ W2,
                                                  const float* __restrict__ b2,
                                                  float* __restrict__ out) {
  const int row = blockIdx.x * 4 + (threadIdx.x >> 6);
  const int lane = threadIdx.x & 63;
  const f16* x = X + (size_t)row * DD;
  float s = 0.f;
#pragma unroll
  for (int c = 0; c < 2; ++c) {
    const int base = lane * 8 + c * 512;
    f16x8 v = *(const f16x8*)(x + base);
#pragma unroll
    for (int e = 0; e < 8; ++e) s += (float)v[e] * W2[base + e];
  }
#pragma unroll
  for (int o = 32; o >= 1; o >>= 1) s += __shfl_xor(s, o);
  if (lane == 0) out[row] = s + b2[0];
}

// ---------------------------------------------------------------------------
extern "C" void kernel_launch(void* const* d_in, const int* in_sizes, int n_in,
                              void* d_out, int out_size, void* d_ws, size_t ws_size,
                              hipStream_t stream) {
  const float* vis = (const float*)d_in[0];
  const float* aud = (const float*)d_in[1];
  const float* Wq = (const float*)d_in[2];
  const float* bq = (const float*)d_in[3];
  const float* Wk = (const float*)d_in[4];
  const float* bk = (const float*)d_in[5];
  const float* Wv = (const float*)d_in[6];
  const float* bv = (const float*)d_in[7];
  const float* Wo = (const float*)d_in[8];
  const float* bo = (const float*)d_in[9];
  const float* W1 = (const float*)d_in[10];
  const float* b1 = (const float*)d_in[11];
  const float* W2 = (const float*)d_in[12];
  const float* b2 = (const float*)d_in[13];
  float* out = (float*)d_out;
  (void)in_sizes; (void)n_in; (void)out_size;

  // ---- fixed workspace carve: weights (10.5 MB) + 4 activation slots (134 MB)
  char* ws = (char*)d_ws;
  size_t off = 0;
  auto carve = [&](size_t bytes) -> void* {
    void* p = ws + off;
    off += (bytes + 255) & ~(size_t)255;
    return p;
  };
  const size_t wtB = (size_t)DD * DD * sizeof(f16);          // 2 MB
  const size_t bufB = (size_t)MTOT * DD * sizeof(f16);       // 33.55 MB
  f16* WqT = (f16*)carve(wtB);
  f16* WkT = (f16*)carve(wtB);
  f16* WvT = (f16*)carve(wtB);
  f16* WoT = (f16*)carve(wtB);
  f16* W1T = (f16*)carve(wtB);
  f16* slot1 = (f16*)carve(bufB);  // VIS16 -> V16 -> ATT16
  f16* slot2 = (f16*)carve(bufB);  // AUD16 -> VT16 -> H16
  f16* slot3 = (f16*)carve(bufB);  // Q16 -> X16
  f16* slot4 = (f16*)carve(bufB);  // K16

  // ---- adaptive attention chunking based on remaining ws budget ----
  const size_t rem = (ws_size > off) ? ws_size - off : 0;
  const size_t perBatch = (size_t)SS * SS * 6 + 512;  // fp32 scores + f16 P
  int nb = 0;
  for (int c : {8, 4, 2, 1})
    if ((size_t)c * perBatch <= rem) { nb = c; break; }
  int RB = 0;
  if (!nb) {
    for (int r : {1024, 512, 256, 128})
      if ((size_t)r * SS * 6 + 512 <= rem) { RB = r; break; }
    if (!RB) RB = 128;  // last resort; will fault if ws truly too small
  }

  f16* VIS16 = slot1;
  f16* AUD16 = slot2;
  f16* Q16 = slot3;
  f16* K16 = slot4;
  f16* V16 = slot1;    // VIS dead after Q proj
  f16* VT16 = slot2;   // AUD dead after K,V proj
  f16* ATT16 = slot1;  // V dead after transpose
  f16* H16 = slot2;    // VT dead after PV
  f16* X16 = slot3;    // Q dead after scores

  const dim3 blk(256);
  const int n4 = MTOT * DD / 4;

  // 1. cast inputs to fp16
  cast_f32_f16<<<dim3((n4 + 255) / 256), blk, 0, stream>>>(vis, VIS16, n4);
  cast_f32_f16<<<dim3((n4 + 255) / 256), blk, 0, stream>>>(aud, AUD16, n4);

  // 2. transpose + cast weights
  transpose_cast_wt<<<dim3(DD / 32, DD / 32), blk, 0, stream>>>(Wq, WqT, DD);
  transpose_cast_wt<<<dim3(DD / 32, DD / 32), blk, 0, stream>>>(Wk, WkT, DD);
  transpose_cast_wt<<<dim3(DD / 32, DD / 32), blk, 0, stream>>>(Wv, WvT, DD);
  transpose_cast_wt<<<dim3(DD / 32, DD / 32), blk, 0, stream>>>(Wo, WoT, DD);
  transpose_cast_wt<<<dim3(DD / 32, DD / 32), blk, 0, stream>>>(W1, W1T, DD);

  // 3. projections: Q from visual; K,V from audio
  gemm_f16<0><<<dim3(DD / 128, MTOT / 128, 1), blk, 0, stream>>>(
      VIS16, WqT, Q16, bq, nullptr, DD, DD, 0, 0, 0);
  gemm_f16<0><<<dim3(DD / 128, MTOT / 128, 1), blk, 0, stream>>>(
      AUD16, WkT, K16, bk, nullptr, DD, DD, 0, 0, 0);
  gemm_f16<0><<<dim3(DD / 128, MTOT / 128, 1), blk, 0, stream>>>(
      AUD16, WvT, V16, bv, nullptr, DD, DD, 0, 0, 0);

  // 4. V -> VT per batch ([S,D] -> [D,S])
  transpose_f16_batch<<<dim3(DD / 32, SS / 32, BB), blk, 0, stream>>>(V16, VT16, SS, DD);

  // 5-7. scores -> softmax -> PV, chunked to fit workspace
  if (nb) {
    float* S32 = (float*)carve((size_t)nb * SS * SS * sizeof(float));
    f16* Pc = (f16*)carve((size_t)nb * SS * SS * sizeof(f16));
    for (int b = 0; b < BB; b += nb) {
      gemm_f16<1><<<dim3(SS / 128, SS / 128, nb), blk, 0, stream>>>(
          Q16 + (size_t)b * SS * DD, K16 + (size_t)b * SS * DD, S32, nullptr, nullptr,
          SS, DD, (size_t)SS * DD, (size_t)SS * DD, (size_t)SS * SS);
      softmax_rows<<<dim3(nb * SS), blk, 0, stream>>>(S32, Pc);
      gemm_f16<2><<<dim3(DD / 128, SS / 128, nb), blk, 0, stream>>>(
          Pc, VT16 + (size_t)b * DD * SS, ATT16 + (size_t)b * SS * DD, nullptr, nullptr,
          DD, SS, (size_t)SS * SS, (size_t)DD * SS, (size_t)SS * DD);
    }
  } else {
    float* S32 = (float*)carve((size_t)RB * SS * sizeof(float));
    f16* Pc = (f16*)carve((size_t)RB * SS * sizeof(f16));
    for (int b = 0; b < BB; ++b) {
      for (int r0 = 0; r0 < SS; r0 += RB) {
        gemm_f16<1><<<dim3(SS / 128, RB / 128, 1), blk, 0, stream>>>(
            Q16 + ((size_t)b * SS + r0) * DD, K16 + (size_t)b * SS * DD, S32,
            nullptr, nullptr, SS, DD, 0, 0, 0);
        softmax_rows<<<dim3(RB), blk, 0, stream>>>(S32, Pc);
        gemm_f16<2><<<dim3(DD / 128, RB / 128, 1), blk, 0, stream>>>(
            Pc, VT16 + (size_t)b * DD * SS, ATT16 + ((size_t)b * SS + r0) * DD,
            nullptr, nullptr, DD, SS, 0, 0, 0);
      }
    }
  }

  // 8. h = attended @ Wo + bo + visual(residual)
  gemm_f16<3><<<dim3(DD / 128, MTOT / 128, 1), blk, 0, stream>>>(
      ATT16, WoT, H16, bo, vis, DD, DD, 0, 0, 0);

  // 9. x = relu(h @ W1 + b1)
  gemm_f16<4><<<dim3(DD / 128, MTOT / 128, 1), blk, 0, stream>>>(
      H16, W1T, X16, b1, nullptr, DD, DD, 0, 0, 0);

  // 10. out = x @ W2 + b2
  matvec_out<<<dim3(MTOT / 4), blk, 0, stream>>>(X16, W2, b2, out);
}

// Round 3
// 553.206 us; speedup vs baseline: 1.2281x; 1.2281x over previous
//
#include <hip/hip_runtime.h>
#include <cstdint>
#include <cstddef>

typedef _Float16 f16;
typedef _Float16 f16x8 __attribute__((ext_vector_type(8)));
typedef _Float16 f16x4 __attribute__((ext_vector_type(4)));
typedef float    f32x4 __attribute__((ext_vector_type(4)));

#define AS1 __attribute__((address_space(1)))
#define AS3 __attribute__((address_space(3)))

static constexpr int BB = 8;      // batch
static constexpr int SS = 2048;   // sequence
static constexpr int DD = 1024;   // model dim
static constexpr int MTOT = BB * SS; // 16384

// ---------------------------------------------------------------------------
// elementwise cast f32 -> f16
// ---------------------------------------------------------------------------
__global__ __launch_bounds__(256) void cast_f32_f16(const float* __restrict__ src,
                                                    f16* __restrict__ dst, int n4) {
  int i = blockIdx.x * 256 + threadIdx.x;
  if (i < n4) {
    const float4 f = reinterpret_cast<const float4*>(src)[i];
    f16x4 o = { (f16)f.x, (f16)f.y, (f16)f.z, (f16)f.w };
    reinterpret_cast<f16x4*>(dst)[i] = o;
  }
}

// ---------------------------------------------------------------------------
// weight transpose + cast: WT[n][k] = (f16)W[k][n], D x D
// ---------------------------------------------------------------------------
__global__ __launch_bounds__(256) void transpose_cast_wt(const float* __restrict__ W,
                                                         f16* __restrict__ WT, int D) {
  __shared__ float tile[32][33];
  const int bx = blockIdx.x * 32;
  const int by = blockIdx.y * 32;
  const int tx = threadIdx.x & 31;
  const int ty = threadIdx.x >> 5;
  for (int i = ty; i < 32; i += 8) tile[i][tx] = W[(size_t)(by + i) * D + bx + tx];
  __syncthreads();
  for (int i = ty; i < 32; i += 8)
    WT[(size_t)(bx + i) * D + by + tx] = (f16)tile[tx][i];
}

// ---------------------------------------------------------------------------
// batched f16 transpose: dst[b][c][r] = src[b][r][c]
// ---------------------------------------------------------------------------
__global__ __launch_bounds__(256) void transpose_f16_batch(const f16* __restrict__ src,
                                                           f16* __restrict__ dst,
                                                           int R, int C) {
  __shared__ f16 tile[32][33];
  src += (size_t)blockIdx.z * R * C;
  dst += (size_t)blockIdx.z * R * C;
  const int bx = blockIdx.x * 32;
  const int by = blockIdx.y * 32;
  const int tx = threadIdx.x & 31;
  const int ty = threadIdx.x >> 5;
  for (int i = ty; i < 32; i += 8) tile[i][tx] = src[(size_t)(by + i) * C + bx + tx];
  __syncthreads();
  for (int i = ty; i < 32; i += 8) dst[(size_t)(bx + i) * R + by + tx] = tile[tx][i];
}

// ---------------------------------------------------------------------------
// 8-phase 256x256 GEMM (T1+T2+T3+T4+T5): C[M,N] = A[M,K] * BT[N,K]^T
// 512 thr = 8 waves (2M x 4N), per-wave C 128x64, BK=64, LDS 128 KiB dbuf.
// Race ledger (per K-tile quadrant order Q00,Q10,Q11,Q01):
//   A-halves of a tile fully ds_read by end of phase 2; B-halves by phase 3.
//   Issue: p1,p2 B(t+1)->buf1 | p3,p4 A(t+2)->buf0 | p5,p6 B(t+2)->buf0 |
//          p7,p8 A(t+3)->buf1.  vmcnt(4) at p4/p8 (in-order retire) =>
//   needed tile's 8 loads are oldest of 12 outstanding -> landed.
// EPI: 0 +bias->f16 | 1 ->f32 | 2 ->f16 | 3 +bias+resid(f32)->f16 | 4 +bias,relu->f16
// ---------------------------------------------------------------------------
template <int EPI>
__global__ __launch_bounds__(512, 2) void gemm8(
    const f16* __restrict__ A, const f16* __restrict__ BT, void* __restrict__ Cout,
    const float* __restrict__ bias, const float* __restrict__ resid,
    int N, int K, int gx,
    size_t Abat, size_t Bbat, size_t Cbat) {
  __shared__ f16 smA[2][256 * 64];
  __shared__ f16 smB[2][256 * 64];

  const int bz = blockIdx.z;
  A += (size_t)bz * Abat;
  BT += (size_t)bz * Bbat;

  // bijective XCD swizzle (m204)
  const int nwg = gridDim.x;
  const int q = nwg >> 3, r = nwg & 7;
  const int xcd = blockIdx.x & 7, lin = blockIdx.x >> 3;
  const int wg = (xcd < r ? xcd * (q + 1) : r * (q + 1) + (xcd - r) * q) + lin;
  const int n0 = (wg % gx) * 256;
  const int m0 = (wg / gx) * 256;

  const int tid = threadIdx.x;
  const int w = tid >> 6, lane = tid & 63;
  const int wr = w >> 2, wc = w & 3;   // 2 x 4 wave grid
  const int lg = lane >> 4, lr = lane & 15;
  const int nt = K >> 6;               // K-tiles (even; K multiple of 128)

  f32x4 acc[8][4] = {};
  f16x8 alo[4][2], ahi[4][2], bfr[2][2];

  // stage one 128x64 half-tile (1024 chunks of 16B; 2 loads/thread).
  // LDS linear dest; source granule pre-swizzled: g = gl ^ (row&7)  (rule #21)
  auto stageA = [&](int t, int h, int d) {
#pragma unroll
    for (int l = 0; l < 2; ++l) {
      const int cb = l * 512 + w * 64;          // wave-uniform chunk base
      const int c = cb + lane;
      const int rr = c >> 3;
      const int g = (c & 7) ^ (rr & 7);
      const f16* src = A + (size_t)(m0 + h * 128 + rr) * K + t * 64 + g * 8;
      __builtin_amdgcn_global_load_lds((const AS1 void*)src,
          (AS3 void*)(&smA[d][(h * 1024 + cb) * 8]), 16, 0, 0);
    }
  };
  auto stageB = [&](int t, int h, int d) {
#pragma unroll
    for (int l = 0; l < 2; ++l) {
      const int cb = l * 512 + w * 64;
      const int c = cb + lane;
      const int rr = c >> 3;
      const int g = (c & 7) ^ (rr & 7);
      const f16* src = BT + (size_t)(n0 + h * 128 + rr) * K + t * 64 + g * 8;
      __builtin_amdgcn_global_load_lds((const AS1 void*)src,
          (AS3 void*)(&smB[d][(h * 1024 + cb) * 8]), 16, 0, 0);
    }
  };
  // ds_read fragments with the same XOR swizzle on the read side
  auto lda = [&](f16x8 (&dst)[4][2], int mh, int d) {
#pragma unroll
    for (int i = 0; i < 4; ++i) {
      const int rrow = wr * 128 + (mh * 4 + i) * 16 + lr;
#pragma unroll
      for (int kh = 0; kh < 2; ++kh) {
        const int kg = (kh * 4 + lg) ^ (rrow & 7);
        dst[i][kh] = *(const f16x8*)(&smA[d][rrow * 64 + kg * 8]);
      }
    }
  };
  auto ldb = [&](int nh, int d) {
#pragma unroll
    for (int j = 0; j < 2; ++j) {
      const int nrow = wc * 64 + (nh * 2 + j) * 16 + lr;
#pragma unroll
      for (int kh = 0; kh < 2; ++kh) {
        const int kg = (kh * 4 + lg) ^ (nrow & 7);
        bfr[j][kh] = *(const f16x8*)(&smB[d][nrow * 64 + kg * 8]);
      }
    }
  };
  auto mma = [&](const f16x8 (&a)[4][2], int mh, int nh) {
#pragma unroll
    for (int i = 0; i < 4; ++i)
#pragma unroll
      for (int j = 0; j < 2; ++j)
#pragma unroll
        for (int kh = 0; kh < 2; ++kh)
          acc[mh * 4 + i][nh * 2 + j] = __builtin_amdgcn_mfma_f32_16x16x32_f16(
              a[i][kh], bfr[j][kh], acc[mh * 4 + i][nh * 2 + j], 0, 0, 0);
  };

#define PH_MID()                                                     \
  __builtin_amdgcn_sched_barrier(0);                                 \
  __builtin_amdgcn_s_barrier();                                      \
  asm volatile("s_waitcnt lgkmcnt(0)" ::: "memory");                 \
  __builtin_amdgcn_sched_barrier(0);                                 \
  __builtin_amdgcn_s_setprio(1)
#define PH_END()                                                     \
  __builtin_amdgcn_s_setprio(0);                                     \
  __builtin_amdgcn_sched_barrier(0);                                 \
  __builtin_amdgcn_s_barrier()
#define PH_END_VM4()                                                 \
  __builtin_amdgcn_s_setprio(0);                                     \
  asm volatile("s_waitcnt vmcnt(4)" ::: "memory");                   \
  __builtin_amdgcn_sched_barrier(0);                                 \
  __builtin_amdgcn_s_barrier()
#define PH_END_VM0()                                                 \
  __builtin_amdgcn_s_setprio(0);                                     \
  asm volatile("s_waitcnt vmcnt(0)" ::: "memory");                   \
  __builtin_amdgcn_sched_barrier(0);                                 \
  __builtin_amdgcn_s_barrier()

  // prologue: A(0),B(0)->buf0; A(1)->buf1; wait first 8 of 12 loads
  stageA(0, 0, 0); stageA(0, 1, 0);
  stageB(0, 0, 0); stageB(0, 1, 0);
  if (nt > 1) { stageA(1, 0, 1); stageA(1, 1, 1); }
  asm volatile("s_waitcnt vmcnt(4)" ::: "memory");
  __builtin_amdgcn_sched_barrier(0);
  __builtin_amdgcn_s_barrier();

  for (int t = 0; t < nt; t += 2) {
    const int u = t + 1;
    const bool pok = (t + 2 < nt);
    // P1: Q00(t)
    lda(alo, 0, 0); ldb(0, 0); stageB(u, 0, 1);
    PH_MID(); mma(alo, 0, 0); PH_END();
    // P2: Q10(t)  (A(t) fully consumed after this phase)
    lda(ahi, 1, 0); stageB(u, 1, 1);
    PH_MID(); mma(ahi, 1, 0); PH_END();
    // P3: Q11(t)  (B(t) fully consumed after this phase)
    ldb(1, 0); if (pok) stageA(t + 2, 0, 0);
    PH_MID(); mma(ahi, 1, 1); PH_END();
    // P4: Q01(t); gate tile u's data
    if (pok) stageA(t + 2, 1, 0);
    PH_MID(); mma(alo, 0, 1);
    if (pok) { PH_END_VM4(); } else { PH_END_VM0(); }
    // P5: Q00(u)
    lda(alo, 0, 1); ldb(0, 1); if (pok) stageB(t + 2, 0, 0);
    PH_MID(); mma(alo, 0, 0); PH_END();
    // P6: Q10(u)
    lda(ahi, 1, 1); if (pok) stageB(t + 2, 1, 0);
    PH_MID(); mma(ahi, 1, 0); PH_END();
    // P7: Q11(u)
    ldb(1, 1); if (pok) stageA(t + 3, 0, 1);
    PH_MID(); mma(ahi, 1, 1); PH_END();
    // P8: Q01(u); gate tile t+2's data
    if (pok) stageA(t + 3, 1, 1);
    PH_MID(); mma(alo, 0, 1);
    if (pok) { PH_END_VM4(); } else { PH_END(); }
  }
#undef PH_MID
#undef PH_END
#undef PH_END_VM4
#undef PH_END_VM0

  // epilogue: D mapping col=lane&15, row=(lane>>4)*4+r
#pragma unroll
  for (int I = 0; I < 8; ++I) {
    const int row = m0 + wr * 128 + I * 16 + lg * 4;
#pragma unroll
    for (int J = 0; J < 4; ++J) {
      const int col = n0 + wc * 64 + J * 16 + lr;
      float bval = 0.f;
      if (EPI == 0 || EPI == 3 || EPI == 4) bval = bias[col];
#pragma unroll
      for (int rr = 0; rr < 4; ++rr) {
        float v = acc[I][J][rr] + bval;
        const size_t idx = (size_t)(row + rr) * N + col;
        if (EPI == 3) v += resid[idx];
        if (EPI == 4) v = fmaxf(v, 0.f);
        if (EPI == 1)
          ((float*)Cout)[(size_t)bz * Cbat + idx] = v;
        else
          ((f16*)Cout)[(size_t)bz * Cbat + idx] = (f16)v;
      }
    }
  }
}

// ---------------------------------------------------------------------------
// row softmax: one block per row of 2048 fp32 scores -> f16 probabilities
// ---------------------------------------------------------------------------
__global__ __launch_bounds__(256) void softmax_rows(const float* __restrict__ Sc,
                                                    f16* __restrict__ P) {
  const size_t row = blockIdx.x;
  const float* x = Sc + row * SS;
  f16* p = P + row * SS;
  const int t = threadIdx.x;
  const int wid = t >> 6, lane = t & 63;
  __shared__ float red[8];

  float v[8];
  float mx = -3.4e38f;
#pragma unroll
  for (int i = 0; i < 8; ++i) {
    v[i] = x[t + i * 256];
    mx = fmaxf(mx, v[i]);
  }
#pragma unroll
  for (int o = 32; o >= 1; o >>= 1) mx = fmaxf(mx, __shfl_xor(mx, o));
  if (lane == 0) red[wid] = mx;
  __syncthreads();
  mx = fmaxf(fmaxf(red[0], red[1]), fmaxf(red[2], red[3]));

  float sum = 0.f;
#pragma unroll
  for (int i = 0; i < 8; ++i) {
    v[i] = __expf(v[i] - mx);
    sum += v[i];
  }
#pragma unroll
  for (int o = 32; o >= 1; o >>= 1) sum += __shfl_xor(sum, o);
  if (lane == 0) red[4 + wid] = sum;
  __syncthreads();
  sum = red[4] + red[5] + red[6] + red[7];
  const float inv = 1.0f / sum;
#pragma unroll
  for (int i = 0; i < 8; ++i) p[t + i * 256] = (f16)(v[i] * inv);
}

// ---------------------------------------------------------------------------
// final head: out[m] = sum_k X[m][k]*W2[k] + b2 ; one wave per row
// ---------------------------------------------------------------------------
__global__ __launch_bounds__(256) void matvec_out(const f16* __restrict__ X,
                                                  const float* __restrict__ W2,
                                                  const float* __restrict__ b2,
                                                  float* __restrict__ out) {
  const int row = blockIdx.x * 4 + (threadIdx.x >> 6);
  const int lane = threadIdx.x & 63;
  const f16* x = X + (size_t)row * DD;
  float s = 0.f;
#pragma unroll
  for (int c = 0; c < 2; ++c) {
    const int base = lane * 8 + c * 512;
    f16x8 v = *(const f16x8*)(x + base);
#pragma unroll
    for (int e = 0; e < 8; ++e) s += (float)v[e] * W2[base + e];
  }
#pragma unroll
  for (int o = 32; o >= 1; o >>= 1) s += __shfl_xor(s, o);
  if (lane == 0) out[row] = s + b2[0];
}

// ---------------------------------------------------------------------------
extern "C" void kernel_launch(void* const* d_in, const int* in_sizes, int n_in,
                              void* d_out, int out_size, void* d_ws, size_t ws_size,
                              hipStream_t stream) {
  const float* vis = (const float*)d_in[0];
  const float* aud = (const float*)d_in[1];
  const float* Wq = (const float*)d_in[2];
  const float* bq = (const float*)d_in[3];
  const float* Wk = (const float*)d_in[4];
  const float* bk = (const float*)d_in[5];
  const float* Wv = (const float*)d_in[6];
  const float* bv = (const float*)d_in[7];
  const float* Wo = (const float*)d_in[8];
  const float* bo = (const float*)d_in[9];
  const float* W1 = (const float*)d_in[10];
  const float* b1 = (const float*)d_in[11];
  const float* W2 = (const float*)d_in[12];
  const float* b2 = (const float*)d_in[13];
  float* out = (float*)d_out;
  (void)in_sizes; (void)n_in; (void)out_size;

  char* ws = (char*)d_ws;
  size_t off = 0;
  auto carve = [&](size_t bytes) -> void* {
    void* p = ws + off;
    off += (bytes + 255) & ~(size_t)255;
    return p;
  };
  const size_t wtB = (size_t)DD * DD * sizeof(f16);
  const size_t bufB = (size_t)MTOT * DD * sizeof(f16);
  f16* WqT = (f16*)carve(wtB);
  f16* WkT = (f16*)carve(wtB);
  f16* WvT = (f16*)carve(wtB);
  f16* WoT = (f16*)carve(wtB);
  f16* W1T = (f16*)carve(wtB);
  f16* slot1 = (f16*)carve(bufB);
  f16* slot2 = (f16*)carve(bufB);
  f16* slot3 = (f16*)carve(bufB);
  f16* slot4 = (f16*)carve(bufB);

  const size_t rem = (ws_size > off) ? ws_size - off : 0;
  const size_t perBatch = (size_t)SS * SS * 6 + 512;
  int nb = 0;
  for (int c : {8, 4, 2, 1})
    if ((size_t)c * perBatch <= rem) { nb = c; break; }
  int RB = 0;
  if (!nb) {
    for (int r : {1024, 512, 256})
      if ((size_t)r * SS * 6 + 512 <= rem) { RB = r; break; }
    if (!RB) RB = 256;  // last resort
  }

  f16* VIS16 = slot1;
  f16* AUD16 = slot2;
  f16* Q16 = slot3;
  f16* K16 = slot4;
  f16* V16 = slot1;
  f16* VT16 = slot2;
  f16* ATT16 = slot1;
  f16* H16 = slot2;
  f16* X16 = slot3;

  const dim3 blk(256);
  const dim3 blk8(512);
  const int n4 = MTOT * DD / 4;

  // 1. cast inputs to fp16
  cast_f32_f16<<<dim3((n4 + 255) / 256), blk, 0, stream>>>(vis, VIS16, n4);
  cast_f32_f16<<<dim3((n4 + 255) / 256), blk, 0, stream>>>(aud, AUD16, n4);

  // 2. transpose + cast weights
  transpose_cast_wt<<<dim3(DD / 32, DD / 32), blk, 0, stream>>>(Wq, WqT, DD);
  transpose_cast_wt<<<dim3(DD / 32, DD / 32), blk, 0, stream>>>(Wk, WkT, DD);
  transpose_cast_wt<<<dim3(DD / 32, DD / 32), blk, 0, stream>>>(Wv, WvT, DD);
  transpose_cast_wt<<<dim3(DD / 32, DD / 32), blk, 0, stream>>>(Wo, WoT, DD);
  transpose_cast_wt<<<dim3(DD / 32, DD / 32), blk, 0, stream>>>(W1, W1T, DD);

  // 3. projections (grid: gx = N/256 = 4, gy = M/256 = 64)
  gemm8<0><<<dim3(4 * 64, 1, 1), blk8, 0, stream>>>(
      VIS16, WqT, Q16, bq, nullptr, DD, DD, 4, 0, 0, 0);
  gemm8<0><<<dim3(4 * 64, 1, 1), blk8, 0, stream>>>(
      AUD16, WkT, K16, bk, nullptr, DD, DD, 4, 0, 0, 0);
  gemm8<0><<<dim3(4 * 64, 1, 1), blk8, 0, stream>>>(
      AUD16, WvT, V16, bv, nullptr, DD, DD, 4, 0, 0, 0);

  // 4. V -> VT per batch
  transpose_f16_batch<<<dim3(DD / 32, SS / 32, BB), blk, 0, stream>>>(V16, VT16, SS, DD);

  // 5-7. scores -> softmax -> PV, chunked to fit workspace
  if (nb) {
    float* S32 = (float*)carve((size_t)nb * SS * SS * sizeof(float));
    f16* Pc = (f16*)carve((size_t)nb * SS * SS * sizeof(f16));
    for (int b = 0; b < BB; b += nb) {
      gemm8<1><<<dim3((SS / 256) * (SS / 256), 1, nb), blk8, 0, stream>>>(
          Q16 + (size_t)b * SS * DD, K16 + (size_t)b * SS * DD, S32, nullptr, nullptr,
          SS, DD, SS / 256, (size_t)SS * DD, (size_t)SS * DD, (size_t)SS * SS);
      softmax_rows<<<dim3(nb * SS), blk, 0, stream>>>(S32, Pc);
      gemm8<2><<<dim3((DD / 256) * (SS / 256), 1, nb), blk8, 0, stream>>>(
          Pc, VT16 + (size_t)b * DD * SS, ATT16 + (size_t)b * SS * DD, nullptr, nullptr,
          DD, SS, DD / 256, (size_t)SS * SS, (size_t)DD * SS, (size_t)SS * DD);
    }
  } else {
    float* S32 = (float*)carve((size_t)RB * SS * sizeof(float));
    f16* Pc = (f16*)carve((size_t)RB * SS * sizeof(f16));
    for (int b = 0; b < BB; ++b) {
      for (int r0 = 0; r0 < SS; r0 += RB) {
        gemm8<1><<<dim3((SS / 256) * (RB / 256), 1, 1), blk8, 0, stream>>>(
            Q16 + ((size_t)b * SS + r0) * DD, K16 + (size_t)b * SS * DD, S32,
            nullptr, nullptr, SS, DD, SS / 256, 0, 0, 0);
        softmax_rows<<<dim3(RB), blk, 0, stream>>>(S32, Pc);
        gemm8<2><<<dim3((DD / 256) * (RB / 256), 1, 1), blk8, 0, stream>>>(
            Pc, VT16 + (size_t)b * DD * SS, ATT16 + ((size_t)b * SS + r0) * DD,
            nullptr, nullptr, DD, SS, DD / 256, 0, 0, 0);
      }
    }
  }

  // 8. h = attended @ Wo + bo + visual(residual)
  gemm8<3><<<dim3(4 * 64, 1, 1), blk8, 0, stream>>>(
      ATT16, WoT, H16, bo, vis, DD, DD, 4, 0, 0, 0);

  // 9. x = relu(h @ W1 + b1)
  gemm8<4><<<dim3(4 * 64, 1, 1), blk8, 0, stream>>>(
      H16, W1T, X16, b1, nullptr, DD, DD, 4, 0, 0, 0);

  // 10. out = x @ W2 + b2
  matvec_out<<<dim3(MTOT / 4), blk, 0, stream>>>(X16, W2, b2, out);
}

// Round 4
// 486.768 us; speedup vs baseline: 1.3958x; 1.1365x over previous
//
#include <hip/hip_runtime.h>
#include <cstdint>
#include <cstddef>

typedef _Float16 f16;
typedef _Float16 f16x8 __attribute__((ext_vector_type(8)));
typedef _Float16 f16x4 __attribute__((ext_vector_type(4)));
typedef float    f32x4 __attribute__((ext_vector_type(4)));

#define AS1 __attribute__((address_space(1)))
#define AS3 __attribute__((address_space(3)))

static constexpr int BB = 8;      // batch
static constexpr int SS = 2048;   // sequence
static constexpr int DD = 1024;   // model dim
static constexpr int MTOT = BB * SS; // 16384

// ---------------------------------------------------------------------------
// elementwise cast f32 -> f16
// ---------------------------------------------------------------------------
__global__ __launch_bounds__(256) void cast_f32_f16(const float* __restrict__ src,
                                                    f16* __restrict__ dst, int n4) {
  int i = blockIdx.x * 256 + threadIdx.x;
  if (i < n4) {
    const float4 f = reinterpret_cast<const float4*>(src)[i];
    f16x4 o = { (f16)f.x, (f16)f.y, (f16)f.z, (f16)f.w };
    reinterpret_cast<f16x4*>(dst)[i] = o;
  }
}

// ---------------------------------------------------------------------------
// weight transpose + cast: WT[n][k] = (f16)W[k][n], D x D
// ---------------------------------------------------------------------------
__global__ __launch_bounds__(256) void transpose_cast_wt(const float* __restrict__ W,
                                                         f16* __restrict__ WT, int D) {
  __shared__ float tile[32][33];
  const int bx = blockIdx.x * 32;
  const int by = blockIdx.y * 32;
  const int tx = threadIdx.x & 31;
  const int ty = threadIdx.x >> 5;
  for (int i = ty; i < 32; i += 8) tile[i][tx] = W[(size_t)(by + i) * D + bx + tx];
  __syncthreads();
  for (int i = ty; i < 32; i += 8)
    WT[(size_t)(bx + i) * D + by + tx] = (f16)tile[tx][i];
}

// ---------------------------------------------------------------------------
// batched f16 transpose: dst[b][c][r] = src[b][r][c]
// ---------------------------------------------------------------------------
__global__ __launch_bounds__(256) void transpose_f16_batch(const f16* __restrict__ src,
                                                           f16* __restrict__ dst,
                                                           int R, int C) {
  __shared__ f16 tile[32][33];
  src += (size_t)blockIdx.z * R * C;
  dst += (size_t)blockIdx.z * R * C;
  const int bx = blockIdx.x * 32;
  const int by = blockIdx.y * 32;
  const int tx = threadIdx.x & 31;
  const int ty = threadIdx.x >> 5;
  for (int i = ty; i < 32; i += 8) tile[i][tx] = src[(size_t)(by + i) * C + bx + tx];
  __syncthreads();
  for (int i = ty; i < 32; i += 8) dst[(size_t)(bx + i) * R + by + tx] = tile[tx][i];
}

// ---------------------------------------------------------------------------
// 8-phase 256x256 GEMM (T1+T2+T3+T4+T5): C[M,N] = A[M,K] * BT[N,K]^T
// 512 thr = 8 waves (2M x 4N), per-wave C 128x64, BK=64, LDS 128 KiB dbuf.
// A-base split: bz < zsplit reads A, else A2 (for the split-P PV dispatch).
// EPI: 0 +bias->f16 | 1 ->f32 | 2 ->f16 | 3 +bias+resid(f32)->f16 |
//      4 +bias, relu, dot W2 (passed via `resid`) -> fp32 partials[16][M]
// ---------------------------------------------------------------------------
template <int EPI>
__global__ __launch_bounds__(512, 2) void gemm8(
    const f16* __restrict__ A, const f16* __restrict__ A2, int zsplit,
    const f16* __restrict__ BT, void* __restrict__ Cout,
    const float* __restrict__ bias, const float* __restrict__ resid,
    int N, int K, int gx,
    size_t Abat, size_t Bbat, size_t Cbat) {
  __shared__ f16 smA[2][256 * 64];
  __shared__ f16 smB[2][256 * 64];

  const int bz = blockIdx.z;
  const f16* Ab = (zsplit && bz >= zsplit) ? A2 + (size_t)(bz - zsplit) * Abat
                                           : A + (size_t)bz * Abat;
  BT += (size_t)bz * Bbat;

  // bijective XCD swizzle (m204)
  const int nwg = gridDim.x;
  const int q = nwg >> 3, r = nwg & 7;
  const int xcd = blockIdx.x & 7, lin = blockIdx.x >> 3;
  const int wg = (xcd < r ? xcd * (q + 1) : r * (q + 1) + (xcd - r) * q) + lin;
  const int n0 = (wg % gx) * 256;
  const int m0 = (wg / gx) * 256;

  const int tid = threadIdx.x;
  const int w = tid >> 6, lane = tid & 63;
  const int wr = w >> 2, wc = w & 3;   // 2 x 4 wave grid
  const int lg = lane >> 4, lr = lane & 15;
  const int nt = K >> 6;               // K-tiles (K multiple of 128)

  f32x4 acc[8][4] = {};
  f16x8 alo[4][2], ahi[4][2], bfr[2][2];

  // stage one 128x64 half-tile; LDS linear dest, source granule pre-swizzled
  auto stageA = [&](int t, int h, int d) {
#pragma unroll
    for (int l = 0; l < 2; ++l) {
      const int cb = l * 512 + w * 64;
      const int c = cb + lane;
      const int rr = c >> 3;
      const int g = (c & 7) ^ (rr & 7);
      const f16* src = Ab + (size_t)(m0 + h * 128 + rr) * K + t * 64 + g * 8;
      __builtin_amdgcn_global_load_lds((const AS1 void*)src,
          (AS3 void*)(&smA[d][(h * 1024 + cb) * 8]), 16, 0, 0);
    }
  };
  auto stageB = [&](int t, int h, int d) {
#pragma unroll
    for (int l = 0; l < 2; ++l) {
      const int cb = l * 512 + w * 64;
      const int c = cb + lane;
      const int rr = c >> 3;
      const int g = (c & 7) ^ (rr & 7);
      const f16* src = BT + (size_t)(n0 + h * 128 + rr) * K + t * 64 + g * 8;
      __builtin_amdgcn_global_load_lds((const AS1 void*)src,
          (AS3 void*)(&smB[d][(h * 1024 + cb) * 8]), 16, 0, 0);
    }
  };
  auto lda = [&](f16x8 (&dst)[4][2], int mh, int d) {
#pragma unroll
    for (int i = 0; i < 4; ++i) {
      const int rrow = wr * 128 + (mh * 4 + i) * 16 + lr;
#pragma unroll
      for (int kh = 0; kh < 2; ++kh) {
        const int kg = (kh * 4 + lg) ^ (rrow & 7);
        dst[i][kh] = *(const f16x8*)(&smA[d][rrow * 64 + kg * 8]);
      }
    }
  };
  auto ldb = [&](int nh, int d) {
#pragma unroll
    for (int j = 0; j < 2; ++j) {
      const int nrow = wc * 64 + (nh * 2 + j) * 16 + lr;
#pragma unroll
      for (int kh = 0; kh < 2; ++kh) {
        const int kg = (kh * 4 + lg) ^ (nrow & 7);
        bfr[j][kh] = *(const f16x8*)(&smB[d][nrow * 64 + kg * 8]);
      }
    }
  };
  auto mma = [&](const f16x8 (&a)[4][2], int mh, int nh) {
#pragma unroll
    for (int i = 0; i < 4; ++i)
#pragma unroll
      for (int j = 0; j < 2; ++j)
#pragma unroll
        for (int kh = 0; kh < 2; ++kh)
          acc[mh * 4 + i][nh * 2 + j] = __builtin_amdgcn_mfma_f32_16x16x32_f16(
              a[i][kh], bfr[j][kh], acc[mh * 4 + i][nh * 2 + j], 0, 0, 0);
  };

#define PH_MID()                                                     \
  __builtin_amdgcn_sched_barrier(0);                                 \
  __builtin_amdgcn_s_barrier();                                      \
  asm volatile("s_waitcnt lgkmcnt(0)" ::: "memory");                 \
  __builtin_amdgcn_sched_barrier(0);                                 \
  __builtin_amdgcn_s_setprio(1)
#define PH_END()                                                     \
  __builtin_amdgcn_s_setprio(0);                                     \
  __builtin_amdgcn_sched_barrier(0);                                 \
  __builtin_amdgcn_s_barrier()
#define PH_END_VM4()                                                 \
  __builtin_amdgcn_s_setprio(0);                                     \
  asm volatile("s_waitcnt vmcnt(4)" ::: "memory");                   \
  __builtin_amdgcn_sched_barrier(0);                                 \
  __builtin_amdgcn_s_barrier()
#define PH_END_VM0()                                                 \
  __builtin_amdgcn_s_setprio(0);                                     \
  asm volatile("s_waitcnt vmcnt(0)" ::: "memory");                   \
  __builtin_amdgcn_sched_barrier(0);                                 \
  __builtin_amdgcn_s_barrier()

  // prologue
  stageA(0, 0, 0); stageA(0, 1, 0);
  stageB(0, 0, 0); stageB(0, 1, 0);
  if (nt > 1) { stageA(1, 0, 1); stageA(1, 1, 1); }
  asm volatile("s_waitcnt vmcnt(4)" ::: "memory");
  __builtin_amdgcn_sched_barrier(0);
  __builtin_amdgcn_s_barrier();

  for (int t = 0; t < nt; t += 2) {
    const int u = t + 1;
    const bool pok = (t + 2 < nt);
    lda(alo, 0, 0); ldb(0, 0); stageB(u, 0, 1);
    PH_MID(); mma(alo, 0, 0); PH_END();
    lda(ahi, 1, 0); stageB(u, 1, 1);
    PH_MID(); mma(ahi, 1, 0); PH_END();
    ldb(1, 0); if (pok) stageA(t + 2, 0, 0);
    PH_MID(); mma(ahi, 1, 1); PH_END();
    if (pok) stageA(t + 2, 1, 0);
    PH_MID(); mma(alo, 0, 1);
    if (pok) { PH_END_VM4(); } else { PH_END_VM0(); }
    lda(alo, 0, 1); ldb(0, 1); if (pok) stageB(t + 2, 0, 0);
    PH_MID(); mma(alo, 0, 0); PH_END();
    lda(ahi, 1, 1); if (pok) stageB(t + 2, 1, 0);
    PH_MID(); mma(ahi, 1, 0); PH_END();
    ldb(1, 1); if (pok) stageA(t + 3, 0, 1);
    PH_MID(); mma(ahi, 1, 1); PH_END();
    if (pok) stageA(t + 3, 1, 1);
    PH_MID(); mma(alo, 0, 1);
    if (pok) { PH_END_VM4(); } else { PH_END(); }
  }
#undef PH_MID
#undef PH_END
#undef PH_END_VM4
#undef PH_END_VM0

  if (EPI == 4) {
    // fused relu + W2 (in `resid`) dot -> partials[16][MTOT] (each written once)
    float* part = (float*)Cout;
    const int cq = (n0 >> 6) + wc;
#pragma unroll
    for (int I = 0; I < 8; ++I) {
#pragma unroll
      for (int rr = 0; rr < 4; ++rr) {
        const int row = m0 + wr * 128 + I * 16 + lg * 4 + rr;
        float s = 0.f;
#pragma unroll
        for (int J = 0; J < 4; ++J) {
          const int col = n0 + wc * 64 + J * 16 + lr;
          float v = acc[I][J][rr] + bias[col];
          v = fmaxf(v, 0.f);
          s += v * resid[col];
        }
#pragma unroll
        for (int o = 1; o < 16; o <<= 1) s += __shfl_xor(s, o);
        if (lr == 0) part[(size_t)cq * MTOT + row] = s;
      }
    }
    return;
  }

  // epilogue: D mapping col=lane&15, row=(lane>>4)*4+r
#pragma unroll
  for (int I = 0; I < 8; ++I) {
    const int row = m0 + wr * 128 + I * 16 + lg * 4;
#pragma unroll
    for (int J = 0; J < 4; ++J) {
      const int col = n0 + wc * 64 + J * 16 + lr;
      float bval = 0.f;
      if (EPI == 0 || EPI == 3) bval = bias[col];
#pragma unroll
      for (int rr = 0; rr < 4; ++rr) {
        float v = acc[I][J][rr] + bval;
        const size_t idx = (size_t)(row + rr) * N + col;
        if (EPI == 3) v += resid[idx];
        if (EPI == 1)
          ((float*)Cout)[(size_t)bz * Cbat + idx] = v;
        else
          ((f16*)Cout)[(size_t)bz * Cbat + idx] = (f16)v;
      }
    }
  }
}

// ---------------------------------------------------------------------------
// row softmax: one block per row of 2048 fp32 scores -> f16 probabilities
// ---------------------------------------------------------------------------
__global__ __launch_bounds__(256) void softmax_rows(const float* __restrict__ Sc,
                                                    f16* __restrict__ P) {
  const size_t row = blockIdx.x;
  const float* x = Sc + row * SS;
  f16* p = P + row * SS;
  const int t = threadIdx.x;
  const int wid = t >> 6, lane = t & 63;
  __shared__ float red[8];

  float v[8];
  float mx = -3.4e38f;
#pragma unroll
  for (int i = 0; i < 8; ++i) {
    v[i] = x[t + i * 256];
    mx = fmaxf(mx, v[i]);
  }
#pragma unroll
  for (int o = 32; o >= 1; o >>= 1) mx = fmaxf(mx, __shfl_xor(mx, o));
  if (lane == 0) red[wid] = mx;
  __syncthreads();
  mx = fmaxf(fmaxf(red[0], red[1]), fmaxf(red[2], red[3]));

  float sum = 0.f;
#pragma unroll
  for (int i = 0; i < 8; ++i) {
    v[i] = __expf(v[i] - mx);
    sum += v[i];
  }
#pragma unroll
  for (int o = 32; o >= 1; o >>= 1) sum += __shfl_xor(sum, o);
  if (lane == 0) red[4 + wid] = sum;
  __syncthreads();
  sum = red[4] + red[5] + red[6] + red[7];
  const float inv = 1.0f / sum;
#pragma unroll
  for (int i = 0; i < 8; ++i) p[t + i * 256] = (f16)(v[i] * inv);
}

// ---------------------------------------------------------------------------
// out[i] = sum_c partials[c][i] + b2
// ---------------------------------------------------------------------------
__global__ __launch_bounds__(256) void reduce_out(const float* __restrict__ part,
                                                  const float* __restrict__ b2,
                                                  float* __restrict__ out) {
  const int i = blockIdx.x * 256 + threadIdx.x;
  float s = 0.f;
#pragma unroll
  for (int c = 0; c < 16; ++c) s += part[(size_t)c * MTOT + i];
  out[i] = s + b2[0];
}

// ---------------------------------------------------------------------------
extern "C" void kernel_launch(void* const* d_in, const int* in_sizes, int n_in,
                              void* d_out, int out_size, void* d_ws, size_t ws_size,
                              hipStream_t stream) {
  const float* vis = (const float*)d_in[0];
  const float* aud = (const float*)d_in[1];
  const float* Wq = (const float*)d_in[2];
  const float* bq = (const float*)d_in[3];
  const float* Wk = (const float*)d_in[4];
  const float* bk = (const float*)d_in[5];
  const float* Wv = (const float*)d_in[6];
  const float* bv = (const float*)d_in[7];
  const float* Wo = (const float*)d_in[8];
  const float* bo = (const float*)d_in[9];
  const float* W1 = (const float*)d_in[10];
  const float* b1 = (const float*)d_in[11];
  const float* W2 = (const float*)d_in[12];
  const float* b2 = (const float*)d_in[13];
  float* out = (float*)d_out;
  (void)in_sizes; (void)n_in; (void)out_size;

  char* ws = (char*)d_ws;
  size_t off = 0;
  auto carve = [&](size_t bytes) -> void* {
    void* p = ws + off;
    off += (bytes + 255) & ~(size_t)255;
    return p;
  };
  const size_t wtB = (size_t)DD * DD * sizeof(f16);
  const size_t bufB = (size_t)MTOT * DD * sizeof(f16);
  f16* WqT = (f16*)carve(wtB);
  f16* WkT = (f16*)carve(wtB);
  f16* WvT = (f16*)carve(wtB);
  f16* WoT = (f16*)carve(wtB);
  f16* W1T = (f16*)carve(wtB);
  f16* slot1 = (f16*)carve(bufB);  // VIS16 -> V16 -> ATT16
  f16* slot2 = (f16*)carve(bufB);  // AUD16 -> VT16
  f16* slot3 = (f16*)carve(bufB);  // Q16 -> P1 (batches 4-7) -> H16
  f16* slot4 = (f16*)carve(bufB);  // K16 -> partials

  const size_t rem = (ws_size > off) ? ws_size - off : 0;
  const size_t needMain = (size_t)4 * SS * SS * 4 + (size_t)4 * SS * SS * 2 + 512;

  f16* VIS16 = slot1;
  f16* AUD16 = slot2;
  f16* Q16 = slot3;
  f16* K16 = slot4;
  f16* V16 = slot1;
  f16* VT16 = slot2;
  f16* ATT16 = slot1;
  f16* P1 = slot3;
  f16* H16 = slot3;
  float* partials = (float*)slot4;   // 16*16384*4 = 1 MB, K dead by then

  const dim3 blk(256);
  const dim3 blk8(512);
  const int n4 = MTOT * DD / 4;

  // 1. cast inputs to fp16
  cast_f32_f16<<<dim3((n4 + 255) / 256), blk, 0, stream>>>(vis, VIS16, n4);
  cast_f32_f16<<<dim3((n4 + 255) / 256), blk, 0, stream>>>(aud, AUD16, n4);

  // 2. transpose + cast weights
  transpose_cast_wt<<<dim3(DD / 32, DD / 32), blk, 0, stream>>>(Wq, WqT, DD);
  transpose_cast_wt<<<dim3(DD / 32, DD / 32), blk, 0, stream>>>(Wk, WkT, DD);
  transpose_cast_wt<<<dim3(DD / 32, DD / 32), blk, 0, stream>>>(Wv, WvT, DD);
  transpose_cast_wt<<<dim3(DD / 32, DD / 32), blk, 0, stream>>>(Wo, WoT, DD);
  transpose_cast_wt<<<dim3(DD / 32, DD / 32), blk, 0, stream>>>(W1, W1T, DD);

  // 3. projections (grid: gx = 4, 256 blocks)
  gemm8<0><<<dim3(4 * 64, 1, 1), blk8, 0, stream>>>(
      VIS16, nullptr, 0, WqT, Q16, bq, nullptr, DD, DD, 4, 0, 0, 0);
  gemm8<0><<<dim3(4 * 64, 1, 1), blk8, 0, stream>>>(
      AUD16, nullptr, 0, WkT, K16, bk, nullptr, DD, DD, 4, 0, 0, 0);
  gemm8<0><<<dim3(4 * 64, 1, 1), blk8, 0, stream>>>(
      AUD16, nullptr, 0, WvT, V16, bv, nullptr, DD, DD, 4, 0, 0, 0);

  // 4. V -> VT per batch
  transpose_f16_batch<<<dim3(DD / 32, SS / 32, BB), blk, 0, stream>>>(V16, VT16, SS, DD);

  // 5-7. scores -> softmax -> (full P) -> one full-width PV
  if (rem >= needMain) {
    float* S32 = (float*)carve((size_t)4 * SS * SS * sizeof(float)); // 67.1 MB
    f16* P0 = (f16*)carve((size_t)4 * SS * SS * sizeof(f16));        // 33.5 MB
    // chunk 0: batches 0-3
    gemm8<1><<<dim3((SS / 256) * (SS / 256), 1, 4), blk8, 0, stream>>>(
        Q16, nullptr, 0, K16, S32, nullptr, nullptr,
        SS, DD, SS / 256, (size_t)SS * DD, (size_t)SS * DD, (size_t)SS * SS);
    softmax_rows<<<dim3(4 * SS), blk, 0, stream>>>(S32, P0);
    // chunk 1: batches 4-7 (P1 overwrites Q16 only after scores chunk 1 done)
    gemm8<1><<<dim3((SS / 256) * (SS / 256), 1, 4), blk8, 0, stream>>>(
        Q16 + (size_t)4 * SS * DD, nullptr, 0, K16 + (size_t)4 * SS * DD, S32,
        nullptr, nullptr, SS, DD, SS / 256,
        (size_t)SS * DD, (size_t)SS * DD, (size_t)SS * SS);
    softmax_rows<<<dim3(4 * SS), blk, 0, stream>>>(S32, P1);
    // PV: one full-width dispatch, z=8, split-P A base
    gemm8<2><<<dim3((DD / 256) * (SS / 256), 1, 8), blk8, 0, stream>>>(
        P0, P1, 4, VT16, ATT16, nullptr, nullptr,
        DD, SS, DD / 256, (size_t)SS * SS, (size_t)DD * SS, (size_t)SS * DD);
  } else {
    // fallback: row-chunked, half-width (only if ws is unexpectedly small)
    const int RB = 256;
    float* S32 = (float*)carve((size_t)RB * SS * sizeof(float));
    f16* Pc = (f16*)carve((size_t)RB * SS * sizeof(f16));
    for (int b = 0; b < BB; ++b) {
      for (int r0 = 0; r0 < SS; r0 += RB) {
        gemm8<1><<<dim3((SS / 256) * (RB / 256), 1, 1), blk8, 0, stream>>>(
            Q16 + ((size_t)b * SS + r0) * DD, nullptr, 0, K16 + (size_t)b * SS * DD,
            S32, nullptr, nullptr, SS, DD, SS / 256, 0, 0, 0);
        softmax_rows<<<dim3(RB), blk, 0, stream>>>(S32, Pc);
        gemm8<2><<<dim3((DD / 256) * (RB / 256), 1, 1), blk8, 0, stream>>>(
            Pc, nullptr, 0, VT16 + (size_t)b * DD * SS,
            ATT16 + ((size_t)b * SS + r0) * DD, nullptr, nullptr,
            DD, SS, DD / 256, 0, 0, 0);
      }
    }
  }

  // 8. h = attended @ Wo + bo + visual(residual, fp32)  -> slot3 (P1 dead)
  gemm8<3><<<dim3(4 * 64, 1, 1), blk8, 0, stream>>>(
      ATT16, nullptr, 0, WoT, H16, bo, vis, DD, DD, 4, 0, 0, 0);

  // 9+10. x = relu(h @ W1 + b1); fused dot with W2 -> partials
  gemm8<4><<<dim3(4 * 64, 1, 1), blk8, 0, stream>>>(
      H16, nullptr, 0, W1T, partials, b1, W2, DD, DD, 4, 0, 0, 0);

  // 11. out = sum partials + b2
  reduce_out<<<dim3(MTOT / 256), blk, 0, stream>>>(partials, b2, out);
}